// Round 1
// baseline (420.565 us; speedup 1.0000x reference)
//
#include <hip/hip_runtime.h>
#include <stdint.h>

// Problem constants (B,S,D fixed by the reference)
#define B_  4
#define S_  2048
#define D_  1024
#define DK_ 1024
#define DV_ 1024

typedef __attribute__((ext_vector_type(8))) short  short8;   // 8 bf16 = 4 VGPRs (MFMA A/B frag)
typedef __attribute__((ext_vector_type(4))) float  floatx4;  // MFMA C/D frag

// round-to-nearest-even fp32 -> bf16 (bit trick; inputs are normal floats)
__device__ __forceinline__ unsigned short f2bf(float f) {
  union { float f; uint32_t u; } v; v.f = f;
  uint32_t r = v.u + 0x7fffu + ((v.u >> 16) & 1u);
  return (unsigned short)(r >> 16);
}

// ---------------- fp32 -> bf16 elementwise (n divisible by 1024) ----------------
__global__ __launch_bounds__(256) void cvt_f32_bf16(const float* __restrict__ in,
                                                    unsigned short* __restrict__ out, int n4) {
  int i = blockIdx.x * blockDim.x + threadIdx.x;
  if (i >= n4) return;
  float4 v = ((const float4*)in)[i];
  ushort4 o;
  o.x = f2bf(v.x); o.y = f2bf(v.y); o.z = f2bf(v.z); o.w = f2bf(v.w);
  ((ushort4*)out)[i] = o;
}

// ---------------- transpose fp32 [rows,cols] -> bf16 [cols,rows] ----------------
__global__ __launch_bounds__(256) void transpose_f32_bf16(const float* __restrict__ in,
                                                          unsigned short* __restrict__ out,
                                                          int rows, int cols) {
  __shared__ float tile[32][33];  // +1 pad: no bank conflicts
  int bx = blockIdx.x * 32, by = blockIdx.y * 32;
  int tx = threadIdx.x & 31, ty = threadIdx.x >> 5;  // 256 thr: ty 0..7
  for (int r = ty; r < 32; r += 8)
    tile[r][tx] = in[(long)(by + r) * cols + bx + tx];
  __syncthreads();
  for (int r = ty; r < 32; r += 8)
    out[(long)(bx + r) * rows + by + tx] = f2bf(tile[tx][r]);
}

// ---------------- transpose bf16 [rows,cols] -> bf16 [cols,rows], batched on z ----------------
__global__ __launch_bounds__(256) void transpose_bf16_batched(const unsigned short* __restrict__ in,
                                                              unsigned short* __restrict__ out,
                                                              int rows, int cols) {
  in  += (long)blockIdx.z * rows * cols;
  out += (long)blockIdx.z * rows * cols;
  __shared__ unsigned short tile[32][33];
  int bx = blockIdx.x * 32, by = blockIdx.y * 32;
  int tx = threadIdx.x & 31, ty = threadIdx.x >> 5;
  for (int r = ty; r < 32; r += 8)
    tile[r][tx] = in[(long)(by + r) * cols + bx + tx];
  __syncthreads();
  for (int r = ty; r < 32; r += 8)
    out[(long)(bx + r) * rows + by + tx] = tile[tx][r];
}

// ---------------- output store helpers ----------------
__device__ __forceinline__ void storeC(float* p, float v)          { *p = v; }
__device__ __forceinline__ void storeC(unsigned short* p, float v) { *p = f2bf(v); }

// ---------------- bf16 BT GEMM: C[M,N] = scale * (A[M,K] · B[N,K]^T) + bias ----------------
// 128x128 block tile, 4 waves (2x2 of 64x64), BK=32, v_mfma_f32_16x16x32_bf16.
// A-frag: m=lane&15, k=(lane>>4)*8+j ; B-frag: n=lane&15, k=(lane>>4)*8+j (both contiguous
// 16B in a row-major [rows][32] LDS tile -> ds_read_b128). C/D: col=lane&15, row=(lane>>4)*4+reg.
// Register staging this round (ladder step 2); global_load_lds next round.
template <typename OutT>
__global__ __launch_bounds__(256)
void gemm_bt(const unsigned short* __restrict__ A, const unsigned short* __restrict__ Bm,
             OutT* __restrict__ C, const float* __restrict__ bias,
             int M, int N, int K, long sA, long sB, long sC, float scale) {
  __shared__ __align__(16) unsigned short As[128 * 32];
  __shared__ __align__(16) unsigned short Bs[128 * 32];
  const int tid  = threadIdx.x;
  const int lane = tid & 63, wave = tid >> 6;
  const int wm = (wave >> 1) * 64, wn = (wave & 1) * 64;
  const int lm = lane & 15, lq = lane >> 4;
  const long zb = blockIdx.z;
  A  += zb * sA;  Bm += zb * sB;  C += zb * sC;
  const int m0 = blockIdx.y * 128, n0 = blockIdx.x * 128;

  // staging slots: slot s in [0,512): row=s>>2, 8-elem chunk (s&3). thread t owns s=t and s=t+256.
  const int srow = tid >> 2, scol = (tid & 3) * 8;
  const unsigned short* Ag0 = A  + (long)(m0 + srow) * K + scol;
  const unsigned short* Ag1 = Ag0 + 64 * (long)K;
  const unsigned short* Bg0 = Bm + (long)(n0 + srow) * K + scol;
  const unsigned short* Bg1 = Bg0 + 64 * (long)K;
  uint4* AsW0 = (uint4*)&As[srow * 32 + scol];
  uint4* AsW1 = (uint4*)&As[(srow + 64) * 32 + scol];
  uint4* BsW0 = (uint4*)&Bs[srow * 32 + scol];
  uint4* BsW1 = (uint4*)&Bs[(srow + 64) * 32 + scol];

  floatx4 acc[4][4] = {};  // zero-init accumulators (AGPRs)

  for (int k0 = 0; k0 < K; k0 += 32) {
    // global loads issued before the barrier -> overlap previous iteration's MFMAs
    uint4 a0 = *(const uint4*)(Ag0 + k0);
    uint4 a1 = *(const uint4*)(Ag1 + k0);
    uint4 b0 = *(const uint4*)(Bg0 + k0);
    uint4 b1 = *(const uint4*)(Bg1 + k0);
    __syncthreads();              // previous compute done reading LDS
    *AsW0 = a0; *AsW1 = a1; *BsW0 = b0; *BsW1 = b1;
    __syncthreads();              // tiles visible

    short8 af[4], bf[4];
#pragma unroll
    for (int i = 0; i < 4; i++)
      af[i] = *(const short8*)&As[(wm + i * 16 + lm) * 32 + lq * 8];
#pragma unroll
    for (int j = 0; j < 4; j++)
      bf[j] = *(const short8*)&Bs[(wn + j * 16 + lm) * 32 + lq * 8];
#pragma unroll
    for (int i = 0; i < 4; i++)
#pragma unroll
      for (int j = 0; j < 4; j++)
        acc[i][j] = __builtin_amdgcn_mfma_f32_16x16x32_bf16(af[i], bf[j], acc[i][j], 0, 0, 0);
  }

  // epilogue: C/D layout col=lane&15, row=(lane>>4)*4+t
#pragma unroll
  for (int i = 0; i < 4; i++) {
    int row = m0 + wm + i * 16 + lq * 4;
#pragma unroll
    for (int j = 0; j < 4; j++) {
      int col = n0 + wn + j * 16 + lm;
      float bv = bias ? bias[col] : 0.f;
#pragma unroll
      for (int t = 0; t < 4; t++) {
        float val = acc[i][j][t] * scale + bv;
        storeC(C + (long)(row + t) * N + col, val);
      }
    }
  }
}

// ---------------- row softmax: fp32 [rows,2048] -> bf16 probs ----------------
__global__ __launch_bounds__(256) void softmax_rows(const float* __restrict__ Sc,
                                                    unsigned short* __restrict__ P) {
  const long row = blockIdx.x;
  const float* x = Sc + row * 2048;
  unsigned short* p = P + row * 2048;
  const int tid = threadIdx.x;
  float v[8];
  float m = -3.4e38f;
#pragma unroll
  for (int j = 0; j < 8; j++) { v[j] = x[tid + j * 256]; m = fmaxf(m, v[j]); }
#pragma unroll
  for (int off = 32; off > 0; off >>= 1) m = fmaxf(m, __shfl_xor(m, off, 64));
  __shared__ float redm[4], reds[4];
  if ((tid & 63) == 0) redm[tid >> 6] = m;
  __syncthreads();
  m = fmaxf(fmaxf(redm[0], redm[1]), fmaxf(redm[2], redm[3]));
  float s = 0.f;
#pragma unroll
  for (int j = 0; j < 8; j++) { v[j] = __expf(v[j] - m); s += v[j]; }
#pragma unroll
  for (int off = 32; off > 0; off >>= 1) s += __shfl_xor(s, off, 64);
  if ((tid & 63) == 0) reds[tid >> 6] = s;
  __syncthreads();
  s = reds[0] + reds[1] + reds[2] + reds[3];
  float inv = 1.f / s;
#pragma unroll
  for (int j = 0; j < 8; j++) p[tid + j * 256] = f2bf(v[j] * inv);
}

extern "C" void kernel_launch(void* const* d_in, const int* in_sizes, int n_in,
                              void* d_out, int out_size, void* d_ws, size_t ws_size,
                              hipStream_t stream) {
  const float* q_in = (const float*)d_in[0];
  const float* k_in = (const float*)d_in[1];
  const float* v_in = (const float*)d_in[2];
  const float* Wq   = (const float*)d_in[3];
  const float* bq   = (const float*)d_in[4];
  const float* Wk   = (const float*)d_in[5];
  const float* bk   = (const float*)d_in[6];
  const float* Wv   = (const float*)d_in[7];
  const float* bv   = (const float*)d_in[8];
  float* out = (float*)d_out;

  // ---- workspace layout (bytes). scores overlays regions dead by the time it is written. ----
  char* ws = (char*)d_ws;
  const long nX  = (long)B_ * S_ * D_;       // 8388608 elems per tensor
  const long nW  = (long)D_ * DK_;           // 1048576
  unsigned short* qb  = (unsigned short*)(ws);                       // [0, 16MB)
  unsigned short* kb  = qb + nX;                                     // [16, 32MB)
  unsigned short* vb  = kb + nX;                                     // [32, 48MB)
  unsigned short* WqT = vb + nX;                                     // [48, 50MB)
  unsigned short* WkT = WqT + nW;
  unsigned short* WvT = WkT + nW;                                    // ends at 54,525,952
  unsigned short* Vb  = WvT + nW;                                    // V bf16 [B,S,DV], dead after transpose
  unsigned short* Qb  = Vb + nX;
  unsigned short* Kb  = Qb + nX;
  unsigned short* Vt  = Kb + nX;                                     // [B, DV, S]
  float*          scores = (float*)ws;                               // overlay [0, 64MB): qb/kb/vb/WT/Vb dead
  unsigned short* attn   = Vt + nX;                                  // after Vt

  dim3 blk(256);

  // 1) inputs -> bf16
  {
    int n4 = (int)(nX / 4);
    dim3 g(n4 / 256);
    cvt_f32_bf16<<<g, blk, 0, stream>>>(q_in, qb, n4);
    cvt_f32_bf16<<<g, blk, 0, stream>>>(k_in, kb, n4);
    cvt_f32_bf16<<<g, blk, 0, stream>>>(v_in, vb, n4);
  }
  // 2) W^T (bf16) so projections use the BT GEMM
  {
    dim3 g(DK_ / 32, D_ / 32);
    transpose_f32_bf16<<<g, blk, 0, stream>>>(Wq, WqT, D_, DK_);
    transpose_f32_bf16<<<g, blk, 0, stream>>>(Wk, WkT, D_, DK_);
    transpose_f32_bf16<<<g, blk, 0, stream>>>(Wv, WvT, D_, DK_);
  }
  // 3) projections: [8192,1024] x [1024,1024]^T -> bf16
  {
    dim3 g(DK_ / 128, (B_ * S_) / 128, 1);
    gemm_bt<unsigned short><<<g, blk, 0, stream>>>(qb, WqT, Qb, bq, B_ * S_, DK_, D_, 0, 0, 0, 1.f);
    gemm_bt<unsigned short><<<g, blk, 0, stream>>>(kb, WkT, Kb, bk, B_ * S_, DK_, D_, 0, 0, 0, 1.f);
    gemm_bt<unsigned short><<<g, blk, 0, stream>>>(vb, WvT, Vb, bv, B_ * S_, DV_, D_, 0, 0, 0, 1.f);
  }
  // 4) V -> V^T per batch (PV becomes a BT GEMM)
  {
    dim3 g(DV_ / 32, S_ / 32, B_);
    transpose_bf16_batched<<<g, blk, 0, stream>>>(Vb, Vt, S_, DV_);
  }
  // 5) scores = Q K^T / 32 (fp32), batched
  {
    dim3 g(S_ / 128, S_ / 128, B_);
    gemm_bt<float><<<g, blk, 0, stream>>>(Qb, Kb, scores, nullptr, S_, S_, DK_,
                                          (long)S_ * DK_, (long)S_ * DK_, (long)S_ * S_, 0.03125f);
  }
  // 6) softmax rows -> bf16 attn
  {
    dim3 g(B_ * S_);
    softmax_rows<<<g, blk, 0, stream>>>(scores, attn);
  }
  // 7) out = attn @ V  ==  attn[2048,2048] x Vt[1024,2048]^T, fp32 out
  {
    dim3 g(DV_ / 128, S_ / 128, B_);
    gemm_bt<float><<<g, blk, 0, stream>>>(attn, Vt, out, nullptr, S_, DV_, S_,
                                          (long)S_ * S_, (long)DV_ * S_, (long)S_ * DV_, 1.f);
  }
}